// Round 3
// baseline (619.741 us; speedup 1.0000x reference)
//
#include <hip/hip_runtime.h>
#include <math.h>

#define LI 2048
#define LT 384
#define LSEQ 2432
#define DM 2560
#define NH 20
#define DH 128
#define SCALE 0.08838834764831845f

typedef __bf16 bf16x8 __attribute__((ext_vector_type(8)));
typedef __bf16 bf16x4 __attribute__((ext_vector_type(4)));
typedef __bf16 bf16x2 __attribute__((ext_vector_type(2)));
typedef float f32x4 __attribute__((ext_vector_type(4)));

__device__ __forceinline__ void async_copy16(const void* gsrc, void* lds_uniform) {
    __builtin_amdgcn_global_load_lds(
        (const __attribute__((address_space(1))) unsigned int*)gsrc,
        (__attribute__((address_space(3))) unsigned int*)lds_uniform,
        16, 0, 0);
}

// ---------------- f32 -> bf16 conversions ----------------

__global__ __launch_bounds__(256) void cvt8_kernel(
    const float* __restrict__ s0, const float* __restrict__ s1,
    const float* __restrict__ s2, const float* __restrict__ s3,
    const float* __restrict__ s4, const float* __restrict__ s5,
    const float* __restrict__ s6, const float* __restrict__ s7,
    __bf16* __restrict__ dst)
{
    const float* srcs[8] = {s0, s1, s2, s3, s4, s5, s6, s7};
    const float* s = srcs[blockIdx.y];
    __bf16* d = dst + (size_t)blockIdx.y * (size_t)DM * DM;
    int i = blockIdx.x * 256 + threadIdx.x;
    const float4* sp = (const float4*)s + (size_t)i * 2;
    float4 a = sp[0], b = sp[1];
    bf16x8 o = {(__bf16)a.x, (__bf16)a.y, (__bf16)a.z, (__bf16)a.w,
                (__bf16)b.x, (__bf16)b.y, (__bf16)b.z, (__bf16)b.w};
    *((bf16x8*)d + i) = o;
}

__global__ __launch_bounds__(256) void cvt_kernel(
    const float* __restrict__ s, __bf16* __restrict__ d, int n8)
{
    int i = blockIdx.x * 256 + threadIdx.x;
    if (i >= n8) return;
    const float4* sp = (const float4*)s + (size_t)i * 2;
    float4 a = sp[0], b = sp[1];
    bf16x8 o = {(__bf16)a.x, (__bf16)a.y, (__bf16)a.z, (__bf16)a.w,
                (__bf16)b.x, (__bf16)b.y, (__bf16)b.z, (__bf16)b.w};
    *((bf16x8*)d + i) = o;
}

// ---------------- 128x128 bf16 GEMM core (C = A @ B^T + bias, f32 out) ----------------

__device__ __forceinline__ void gemm_core(
    const __bf16* __restrict__ Ab,    // A + m0*2560
    const __bf16* __restrict__ Bb,    // B + n_local*2560
    const float* __restrict__ bias,   // + n_local
    float* __restrict__ Cb,           // C + m0*2560 + n_local (ld = 2560)
    __bf16* sA, __bf16* sB)
{
    const int t = threadIdx.x, wave = t >> 6, lane = t & 63;
    const int l15 = lane & 15, quad = lane >> 4;
    const int wm = wave >> 1, wn = wave & 1;

    f32x4 acc[4][4];
#pragma unroll
    for (int i = 0; i < 4; i++)
#pragma unroll
        for (int j = 0; j < 4; j++) acc[i][j] = f32x4{0.f, 0.f, 0.f, 0.f};

    const int c0 = wave * 64 + lane, c1 = 256 + c0;
    const size_t offA0 = (size_t)(c0 >> 2) * DM + (c0 & 3) * 8;
    const size_t offA1 = (size_t)(c1 >> 2) * DM + (c1 & 3) * 8;

    for (int k0 = 0; k0 < DM; k0 += 32) {
        __syncthreads();
        async_copy16(Ab + offA0 + k0, (char*)sA + wave * 1024);
        async_copy16(Ab + offA1 + k0, (char*)sA + 4096 + wave * 1024);
        async_copy16(Bb + offA0 + k0, (char*)sB + wave * 1024);
        async_copy16(Bb + offA1 + k0, (char*)sB + 4096 + wave * 1024);
        __syncthreads();

        bf16x8 af[4], bg[4];
#pragma unroll
        for (int mt = 0; mt < 4; mt++)
            af[mt] = *(const bf16x8*)(sA + (wm * 64 + mt * 16 + l15) * 32 + quad * 8);
#pragma unroll
        for (int nt = 0; nt < 4; nt++)
            bg[nt] = *(const bf16x8*)(sB + (wn * 64 + nt * 16 + l15) * 32 + quad * 8);
#pragma unroll
        for (int mt = 0; mt < 4; mt++)
#pragma unroll
            for (int nt = 0; nt < 4; nt++)
                acc[mt][nt] = __builtin_amdgcn_mfma_f32_16x16x32_bf16(af[mt], bg[nt], acc[mt][nt], 0, 0, 0);
    }

#pragma unroll
    for (int mt = 0; mt < 4; mt++) {
        const int row = wm * 64 + mt * 16 + quad * 4;
#pragma unroll
        for (int nt = 0; nt < 4; nt++) {
            const int col = wn * 64 + nt * 16 + l15;
            const float bv = bias[col];
            float* cp = Cb + (size_t)row * DM + col;
            cp[0]        = acc[mt][nt][0] + bv;
            cp[DM]       = acc[mt][nt][1] + bv;
            cp[2 * DM]   = acc[mt][nt][2] + bv;
            cp[3 * DM]   = acc[mt][nt][3] + bv;
        }
    }
}

// QKV: 1140 blocks, swizzled so 4 n-tiles x 19 m-tiles (76 blocks) form an L2 group.
__global__ __launch_bounds__(256, 4) void gemm_qkv_kernel(
    const __bf16* __restrict__ xbf, const __bf16* __restrict__ wbf,
    const float* __restrict__ bq, const float* __restrict__ bk, const float* __restrict__ bv,
    const float* __restrict__ bq_t, const float* __restrict__ bk_t, const float* __restrict__ bv_t,
    float* __restrict__ qraw, float* __restrict__ kraw, float* __restrict__ vraw)
{
    __shared__ alignas(16) __bf16 sA[128 * 32];
    __shared__ alignas(16) __bf16 sB[128 * 32];
    const int lin = blockIdx.x;
    const int group = lin / 76, rem = lin % 76;
    const int mblk = rem >> 2;
    const int nblk = group * 4 + (rem & 3);
    const int which = nblk / 20;               // 0=Q 1=K 2=V
    const int nloc = (nblk % 20) * 128;
    const bool is_txt = (mblk >= 16);
    const size_t WELEM = (size_t)DM * DM;
    const int widx = which + (is_txt ? 4 : 0);
    const __bf16* W = wbf + (size_t)widx * WELEM;
    const float* bias = (which == 0) ? (is_txt ? bq_t : bq)
                      : (which == 1) ? (is_txt ? bk_t : bk)
                                     : (is_txt ? bv_t : bv);
    float* C = (which == 0) ? qraw : (which == 1) ? kraw : vraw;
    gemm_core(xbf + (size_t)mblk * 128 * DM, W + (size_t)nloc * DM, bias + nloc,
              C + (size_t)mblk * 128 * DM + nloc, sA, sB);
}

// Out-proj: 380 blocks, same 76-block grouping.
__global__ __launch_bounds__(256, 4) void gemm_out_kernel(
    const __bf16* __restrict__ attnbf, const __bf16* __restrict__ wbf,
    const float* __restrict__ bo, const float* __restrict__ bo_t,
    float* __restrict__ out)
{
    __shared__ alignas(16) __bf16 sA[128 * 32];
    __shared__ alignas(16) __bf16 sB[128 * 32];
    const int lin = blockIdx.x;
    const int group = lin / 76, rem = lin % 76;
    const int mblk = rem >> 2;
    const int nblk = group * 4 + (rem & 3);
    const bool is_txt = (mblk >= 16);
    const size_t WELEM = (size_t)DM * DM;
    const __bf16* W = wbf + (size_t)(is_txt ? 7 : 3) * WELEM;
    const float* bias = (is_txt ? bo_t : bo) + nblk * 128;
    gemm_core(attnbf + (size_t)mblk * 128 * DM, W + (size_t)nblk * 128 * DM, bias,
              out + (size_t)mblk * 128 * DM + nblk * 128, sA, sB);
}

// ---------------- RMS norm + qn/kn + mask + RoPE, f32 -> bf16 ----------------

__global__ __launch_bounds__(256) void rmsrope_kernel(
    const float* __restrict__ qraw, const float* __restrict__ kraw,
    const float* __restrict__ rope, const float* __restrict__ img_masks,
    const float* __restrict__ qn, const float* __restrict__ kn,
    const float* __restrict__ qn_t, const float* __restrict__ kn_t,
    __bf16* __restrict__ qbf, __bf16* __restrict__ kbf)
{
    const int l = blockIdx.x, t = threadIdx.x;
    const int wave = t >> 6, lane = t & 63;
    const bool is_img = (l < LI);
    const float* qw = is_img ? qn : qn_t;
    const float* kw = is_img ? kn : kn_t;
    const float kmask = is_img ? img_masks[l] : 1.0f;
    const float* qr = qraw + (size_t)l * DM;
    const float* kr = kraw + (size_t)l * DM;

    float2 qv[5], kv[5];
    float sq = 0.f, sk = 0.f;
#pragma unroll
    for (int j = 0; j < 5; j++) {
        int c2 = j * 256 + t;
        qv[j] = *(const float2*)(qr + 2 * c2);
        kv[j] = *(const float2*)(kr + 2 * c2);
        sq += qv[j].x * qv[j].x + qv[j].y * qv[j].y;
        sk += kv[j].x * kv[j].x + kv[j].y * kv[j].y;
    }
#pragma unroll
    for (int m = 32; m; m >>= 1) { sq += __shfl_xor(sq, m); sk += __shfl_xor(sk, m); }
    __shared__ float redq[4], redk[4];
    if (lane == 0) { redq[wave] = sq; redk[wave] = sk; }
    __syncthreads();
    sq = redq[0] + redq[1] + redq[2] + redq[3];
    sk = redk[0] + redk[1] + redk[2] + redk[3];
    const float rq = rsqrtf(sq * (1.0f / DM) + 1e-5f);
    const float rk = rsqrtf(sk * (1.0f / DM) + 1e-5f) * kmask;

#pragma unroll
    for (int j = 0; j < 5; j++) {
        int c2 = j * 256 + t;
        int c = 2 * c2;
        float4 rp = *(const float4*)(rope + ((size_t)l * 64 + (c2 & 63)) * 4);
        float2 w2q = *(const float2*)(qw + c);
        float2 w2k = *(const float2*)(kw + c);
        float x0 = qv[j].x * rq * w2q.x, x1 = qv[j].y * rq * w2q.y;
        bf16x2 oq = {(__bf16)(rp.x * x0 + rp.y * x1), (__bf16)(rp.z * x0 + rp.w * x1)};
        *(bf16x2*)(qbf + (size_t)l * DM + c) = oq;
        float y0 = kv[j].x * rk * w2k.x, y1 = kv[j].y * rk * w2k.y;
        bf16x2 ok = {(__bf16)(rp.x * y0 + rp.y * y1), (__bf16)(rp.z * y0 + rp.w * y1)};
        *(bf16x2*)(kbf + (size_t)l * DM + c) = ok;
    }
}

// ---------------- transpose V (L,DM) f32 -> (DM,L) bf16 ----------------

__global__ __launch_bounds__(256) void transpose_cvt_kernel(
    const float* __restrict__ src, __bf16* __restrict__ dst)
{
    __shared__ float tile[32][33];
    const int c0 = blockIdx.x * 32;
    const int r0 = blockIdx.y * 32;
    const int tc = threadIdx.x & 31, tr = threadIdx.x >> 5;
#pragma unroll
    for (int j = 0; j < 4; j++)
        tile[tr + j * 8][tc] = src[(size_t)(r0 + tr + j * 8) * DM + c0 + tc];
    __syncthreads();
#pragma unroll
    for (int j = 0; j < 4; j++)
        dst[(size_t)(c0 + tr + j * 8) * LSEQ + r0 + tc] = (__bf16)tile[tc][tr + j * 8];
}

// ---------------- flash attention ----------------

__global__ __launch_bounds__(256, 4) void flash_kernel(
    const __bf16* __restrict__ qb, const __bf16* __restrict__ kb,
    const __bf16* __restrict__ vt, __bf16* __restrict__ ob)
{
    __shared__ alignas(16) __bf16 sK[64 * DH];      // [kv 64][d 128]
    __shared__ alignas(16) __bf16 sV[DH * 64];      // [d 128][kv 64]
    __shared__ alignas(16) __bf16 sP[4 * 16 * 64];  // per-wave [q 16][kv 64]
    const int head = blockIdx.x;
    const int q0 = blockIdx.y * 64;
    const int t = threadIdx.x, wave = t >> 6, lane = t & 63;
    const int l15 = lane & 15, quad = lane >> 4;
    const int qrow = q0 + wave * 16 + l15;

    bf16x8 aq[4];
#pragma unroll
    for (int d = 0; d < 4; d++)
        aq[d] = *(const bf16x8*)(qb + (size_t)qrow * DM + head * DH + d * 32 + quad * 8);

    size_t koff[4], voff[4];
#pragma unroll
    for (int j = 0; j < 4; j++) {
        int ck = (wave * 4 + j) * 64 + lane;
        int krow = ck >> 4, ku = (ck & 15) ^ (krow & 7);
        koff[j] = (size_t)krow * DM + head * DH + ku * 8;
        int cv = (wave * 4 + j) * 64 + lane;
        int vrow = cv >> 3, vu = (cv & 7) ^ (vrow & 7);
        voff[j] = (size_t)(head * DH + vrow) * LSEQ + vu * 8;
    }

    f32x4 o[8];
#pragma unroll
    for (int i = 0; i < 8; i++) o[i] = f32x4{0.f, 0.f, 0.f, 0.f};
    float m_i = -INFINITY, l_i = 0.f;
    __bf16* pw = sP + wave * (16 * 64);

    for (int kv0 = 0; kv0 < LSEQ; kv0 += 64) {
        __syncthreads();
#pragma unroll
        for (int j = 0; j < 4; j++)
            async_copy16(kb + koff[j] + (size_t)kv0 * DM, (char*)sK + (wave * 4 + j) * 1024);
#pragma unroll
        for (int j = 0; j < 4; j++)
            async_copy16(vt + voff[j] + kv0, (char*)sV + (wave * 4 + j) * 1024);
        __syncthreads();

        f32x4 st[4];
#pragma unroll
        for (int b = 0; b < 4; b++) {
            st[b] = f32x4{0.f, 0.f, 0.f, 0.f};
#pragma unroll
            for (int d = 0; d < 4; d++) {
                int row = b * 16 + l15;
                bf16x8 ak = *(const bf16x8*)(sK + row * 128 + (((d * 4 + quad) ^ (row & 7)) * 8));
                st[b] = __builtin_amdgcn_mfma_f32_16x16x32_bf16(ak, aq[d], st[b], 0, 0, 0);
            }
        }

        float mx = m_i;
#pragma unroll
        for (int b = 0; b < 4; b++)
#pragma unroll
            for (int r = 0; r < 4; r++) { st[b][r] *= SCALE; mx = fmaxf(mx, st[b][r]); }
        mx = fmaxf(mx, __shfl_xor(mx, 16));
        mx = fmaxf(mx, __shfl_xor(mx, 32));
        const float al = __expf(m_i - mx);
        m_i = mx;
        float sum = 0.f;
#pragma unroll
        for (int b = 0; b < 4; b++)
#pragma unroll
            for (int r = 0; r < 4; r++) {
                float p = __expf(st[b][r] - mx);
                st[b][r] = p;
                sum += p;
            }
        sum += __shfl_xor(sum, 16);
        sum += __shfl_xor(sum, 32);
        l_i = l_i * al + sum;

#pragma unroll
        for (int b = 0; b < 4; b++) {
            bf16x4 pk = {(__bf16)st[b][0], (__bf16)st[b][1], (__bf16)st[b][2], (__bf16)st[b][3]};
            int u = 2 * b + (quad >> 1);
            *(bf16x4*)(pw + l15 * 64 + ((u ^ (l15 & 7)) * 8) + (quad & 1) * 4) = pk;
        }

        float alr[4];
#pragma unroll
        for (int r = 0; r < 4; r++) alr[r] = __shfl(al, quad * 4 + r);
#pragma unroll
        for (int i = 0; i < 8; i++) {
            f32x4 tmp = o[i];
            tmp[0] *= alr[0]; tmp[1] *= alr[1]; tmp[2] *= alr[2]; tmp[3] *= alr[3];
            o[i] = tmp;
        }
        __asm__ volatile("s_waitcnt lgkmcnt(0)" ::: "memory");

        bf16x8 ap0 = *(const bf16x8*)(pw + l15 * 64 + ((quad ^ (l15 & 7)) * 8));
        bf16x8 ap1 = *(const bf16x8*)(pw + l15 * 64 + (((4 + quad) ^ (l15 & 7)) * 8));
#pragma unroll
        for (int n2 = 0; n2 < 8; n2++) {
            int row = n2 * 16 + l15;
            bf16x8 bv0 = *(const bf16x8*)(sV + row * 64 + ((quad ^ (row & 7)) * 8));
            bf16x8 bv1 = *(const bf16x8*)(sV + row * 64 + (((4 + quad) ^ (row & 7)) * 8));
            o[n2] = __builtin_amdgcn_mfma_f32_16x16x32_bf16(ap0, bv0, o[n2], 0, 0, 0);
            o[n2] = __builtin_amdgcn_mfma_f32_16x16x32_bf16(ap1, bv1, o[n2], 0, 0, 0);
        }
    }

    const float inv = 1.0f / l_i;
    float invr[4];
#pragma unroll
    for (int r = 0; r < 4; r++) invr[r] = __shfl(inv, quad * 4 + r);
#pragma unroll
    for (int n2 = 0; n2 < 8; n2++)
#pragma unroll
        for (int r = 0; r < 4; r++)
            ob[(size_t)(q0 + wave * 16 + quad * 4 + r) * DM + head * DH + n2 * 16 + l15] =
                (__bf16)(o[n2][r] * invr[r]);
}

// ---------------- launch ----------------

extern "C" void kernel_launch(void* const* d_in, const int* in_sizes, int n_in,
                              void* d_out, int out_size, void* d_ws, size_t ws_size,
                              hipStream_t stream) {
    const float* img       = (const float*)d_in[0];
    const float* txt       = (const float*)d_in[1];
    const float* rope      = (const float*)d_in[2];
    const float* img_masks = (const float*)d_in[3];
    const float* Wq   = (const float*)d_in[4];  const float* bq   = (const float*)d_in[5];
    const float* Wk   = (const float*)d_in[6];  const float* bk   = (const float*)d_in[7];
    const float* Wv   = (const float*)d_in[8];  const float* bv   = (const float*)d_in[9];
    const float* Wo   = (const float*)d_in[10]; const float* bo   = (const float*)d_in[11];
    const float* Wq_t = (const float*)d_in[12]; const float* bq_t = (const float*)d_in[13];
    const float* Wk_t = (const float*)d_in[14]; const float* bk_t = (const float*)d_in[15];
    const float* Wv_t = (const float*)d_in[16]; const float* bv_t = (const float*)d_in[17];
    const float* Wo_t = (const float*)d_in[18]; const float* bo_t = (const float*)d_in[19];
    const float* qn   = (const float*)d_in[20]; const float* kn   = (const float*)d_in[21];
    const float* qn_t = (const float*)d_in[22]; const float* kn_t = (const float*)d_in[23];
    float* out = (float*)d_out;

    const size_t WELEM = (size_t)DM * DM;
    const size_t XELEM = (size_t)LSEQ * DM;

    __bf16* wbf  = (__bf16*)d_ws;
    __bf16* xbf  = wbf + 8 * WELEM;
    float*  qraw = (float*)(xbf + XELEM);
    float*  kraw = qraw + XELEM;
    float*  vraw = kraw + XELEM;
    __bf16* qbf  = (__bf16*)(vraw + XELEM);
    __bf16* kbf  = qbf + XELEM;
    __bf16* vt   = kbf + XELEM;
    __bf16* attnbf = (__bf16*)qraw;                // reuse (qraw dead after rmsrope)

    cvt8_kernel<<<dim3((int)(WELEM / 8 / 256), 8), 256, 0, stream>>>(
        Wq, Wk, Wv, Wo, Wq_t, Wk_t, Wv_t, Wo_t, wbf);
    cvt_kernel<<<dim3((LI * DM / 8 + 255) / 256), 256, 0, stream>>>(img, xbf, LI * DM / 8);
    cvt_kernel<<<dim3((LT * DM / 8 + 255) / 256), 256, 0, stream>>>(
        txt, xbf + (size_t)LI * DM, LT * DM / 8);

    gemm_qkv_kernel<<<dim3(1140), 256, 0, stream>>>(
        xbf, wbf, bq, bk, bv, bq_t, bk_t, bv_t, qraw, kraw, vraw);

    rmsrope_kernel<<<dim3(LSEQ), 256, 0, stream>>>(
        qraw, kraw, rope, img_masks, qn, kn, qn_t, kn_t, qbf, kbf);

    transpose_cvt_kernel<<<dim3(DM / 32, LSEQ / 32), 256, 0, stream>>>(vraw, vt);

    flash_kernel<<<dim3(NH, LSEQ / 64), 256, 0, stream>>>(qbf, kbf, vt, attnbf);

    gemm_out_kernel<<<dim3(380), 256, 0, stream>>>(attnbf, wbf, bo, bo_t, out);
}

// Round 4
// 579.814 us; speedup vs baseline: 1.0689x; 1.0689x over previous
//
#include <hip/hip_runtime.h>
#include <math.h>

#define LI 2048
#define LT 384
#define LSEQ 2432
#define DM 2560
#define NH 20
#define DH 128
#define SCALE 0.08838834764831845f

typedef __bf16 bf16x8 __attribute__((ext_vector_type(8)));
typedef __bf16 bf16x4 __attribute__((ext_vector_type(4)));
typedef __bf16 bf16x2 __attribute__((ext_vector_type(2)));
typedef float f32x4 __attribute__((ext_vector_type(4)));

__device__ __forceinline__ void async_copy16(const void* gsrc, void* lds_uniform) {
    __builtin_amdgcn_global_load_lds(
        (const __attribute__((address_space(1))) unsigned int*)gsrc,
        (__attribute__((address_space(3))) unsigned int*)lds_uniform,
        16, 0, 0);
}

// ---------------- f32 -> bf16 conversions ----------------

__global__ __launch_bounds__(256) void cvt8_kernel(
    const float* __restrict__ s0, const float* __restrict__ s1,
    const float* __restrict__ s2, const float* __restrict__ s3,
    const float* __restrict__ s4, const float* __restrict__ s5,
    const float* __restrict__ s6, const float* __restrict__ s7,
    __bf16* __restrict__ dst)
{
    const float* srcs[8] = {s0, s1, s2, s3, s4, s5, s6, s7};
    const float* s = srcs[blockIdx.y];
    __bf16* d = dst + (size_t)blockIdx.y * (size_t)DM * DM;
    int i = blockIdx.x * 256 + threadIdx.x;
    const float4* sp = (const float4*)s + (size_t)i * 2;
    float4 a = sp[0], b = sp[1];
    bf16x8 o = {(__bf16)a.x, (__bf16)a.y, (__bf16)a.z, (__bf16)a.w,
                (__bf16)b.x, (__bf16)b.y, (__bf16)b.z, (__bf16)b.w};
    *((bf16x8*)d + i) = o;
}

__global__ __launch_bounds__(256) void cvt_kernel(
    const float* __restrict__ s, __bf16* __restrict__ d, int n8)
{
    int i = blockIdx.x * 256 + threadIdx.x;
    if (i >= n8) return;
    const float4* sp = (const float4*)s + (size_t)i * 2;
    float4 a = sp[0], b = sp[1];
    bf16x8 o = {(__bf16)a.x, (__bf16)a.y, (__bf16)a.z, (__bf16)a.w,
                (__bf16)b.x, (__bf16)b.y, (__bf16)b.z, (__bf16)b.w};
    *((bf16x8*)d + i) = o;
}

// ---------------- 128x128 bf16 GEMM core, BK=64, XOR-swizzled LDS ----------------
// C = A @ B^T + bias (f32 out). A: (M,2560), B: (N,2560) bf16 row-major.
// LDS tiles 128x64, 8 16B-units per row; physical unit = logical ^ (row&7).

__device__ __forceinline__ void gemm_core(
    const __bf16* __restrict__ Ab,    // A + m0*2560
    const __bf16* __restrict__ Bb,    // B + n_local*2560
    const float* __restrict__ bias,   // + n_local
    float* __restrict__ Cb,           // C + m0*2560 + n_local (ld = 2560)
    __bf16* sA, __bf16* sB)
{
    const int t = threadIdx.x, wave = t >> 6, lane = t & 63;
    const int l15 = lane & 15, quad = lane >> 4;
    const int wm = wave >> 1, wn = wave & 1;

    f32x4 acc[4][4];
#pragma unroll
    for (int i = 0; i < 4; i++)
#pragma unroll
        for (int j = 0; j < 4; j++) acc[i][j] = f32x4{0.f, 0.f, 0.f, 0.f};

    // staging source offsets (swizzle inverted): unit c = j*256 + t
    size_t soff[4];
#pragma unroll
    for (int j = 0; j < 4; j++) {
        int c = j * 256 + t;
        int row = c >> 3, u = c & 7;
        soff[j] = (size_t)row * DM + ((u ^ (row & 7)) * 8);
    }

    for (int k0 = 0; k0 < DM; k0 += 64) {
        __syncthreads();
#pragma unroll
        for (int j = 0; j < 4; j++)
            async_copy16(Ab + soff[j] + k0, (char*)sA + (j * 256 + wave * 64) * 16);
#pragma unroll
        for (int j = 0; j < 4; j++)
            async_copy16(Bb + soff[j] + k0, (char*)sB + (j * 256 + wave * 64) * 16);
        __syncthreads();

#pragma unroll
        for (int ks = 0; ks < 2; ks++) {
            bf16x8 af[4], bg[4];
#pragma unroll
            for (int mt = 0; mt < 4; mt++) {
                int r = wm * 64 + mt * 16 + l15;
                af[mt] = *(const bf16x8*)(sA + r * 64 + (((quad + ks * 4) ^ (r & 7)) * 8));
            }
#pragma unroll
            for (int nt = 0; nt < 4; nt++) {
                int r = wn * 64 + nt * 16 + l15;
                bg[nt] = *(const bf16x8*)(sB + r * 64 + (((quad + ks * 4) ^ (r & 7)) * 8));
            }
#pragma unroll
            for (int mt = 0; mt < 4; mt++)
#pragma unroll
                for (int nt = 0; nt < 4; nt++)
                    acc[mt][nt] = __builtin_amdgcn_mfma_f32_16x16x32_bf16(af[mt], bg[nt], acc[mt][nt], 0, 0, 0);
        }
    }

#pragma unroll
    for (int mt = 0; mt < 4; mt++) {
        const int row = wm * 64 + mt * 16 + quad * 4;
#pragma unroll
        for (int nt = 0; nt < 4; nt++) {
            const int col = wn * 64 + nt * 16 + l15;
            const float bv = bias[col];
            float* cp = Cb + (size_t)row * DM + col;
            cp[0]        = acc[mt][nt][0] + bv;
            cp[DM]       = acc[mt][nt][1] + bv;
            cp[2 * DM]   = acc[mt][nt][2] + bv;
            cp[3 * DM]   = acc[mt][nt][3] + bv;
        }
    }
}

// QKV: grid (60, 19) — n fastest (R2 mapping, best measured FETCH).
__global__ __launch_bounds__(256, 4) void gemm_qkv_kernel(
    const __bf16* __restrict__ xbf, const __bf16* __restrict__ wbf,
    const float* __restrict__ bq, const float* __restrict__ bk, const float* __restrict__ bv,
    const float* __restrict__ bq_t, const float* __restrict__ bk_t, const float* __restrict__ bv_t,
    float* __restrict__ qraw, float* __restrict__ kraw, float* __restrict__ vraw)
{
    __shared__ alignas(16) __bf16 sA[128 * 64];
    __shared__ alignas(16) __bf16 sB[128 * 64];
    const int nblk = blockIdx.x, mblk = blockIdx.y;
    const int which = nblk / 20;               // 0=Q 1=K 2=V
    const int nloc = (nblk % 20) * 128;
    const bool is_txt = (mblk >= 16);
    const size_t WELEM = (size_t)DM * DM;
    const int widx = which + (is_txt ? 4 : 0);
    const __bf16* W = wbf + (size_t)widx * WELEM;
    const float* bias = (which == 0) ? (is_txt ? bq_t : bq)
                      : (which == 1) ? (is_txt ? bk_t : bk)
                                     : (is_txt ? bv_t : bv);
    float* C = (which == 0) ? qraw : (which == 1) ? kraw : vraw;
    gemm_core(xbf + (size_t)mblk * 128 * DM, W + (size_t)nloc * DM, bias + nloc,
              C + (size_t)mblk * 128 * DM + nloc, sA, sB);
}

// Out-proj: grid (20, 19).
__global__ __launch_bounds__(256, 4) void gemm_out_kernel(
    const __bf16* __restrict__ attnbf, const __bf16* __restrict__ wbf,
    const float* __restrict__ bo, const float* __restrict__ bo_t,
    float* __restrict__ out)
{
    __shared__ alignas(16) __bf16 sA[128 * 64];
    __shared__ alignas(16) __bf16 sB[128 * 64];
    const int nblk = blockIdx.x, mblk = blockIdx.y;
    const bool is_txt = (mblk >= 16);
    const size_t WELEM = (size_t)DM * DM;
    const __bf16* W = wbf + (size_t)(is_txt ? 7 : 3) * WELEM;
    const float* bias = (is_txt ? bo_t : bo) + nblk * 128;
    gemm_core(attnbf + (size_t)mblk * 128 * DM, W + (size_t)nblk * 128 * DM, bias,
              out + (size_t)mblk * 128 * DM + nblk * 128, sA, sB);
}

// ---------------- RMS norm + qn/kn + mask + RoPE, f32 -> bf16 ----------------

__global__ __launch_bounds__(256) void rmsrope_kernel(
    const float* __restrict__ qraw, const float* __restrict__ kraw,
    const float* __restrict__ rope, const float* __restrict__ img_masks,
    const float* __restrict__ qn, const float* __restrict__ kn,
    const float* __restrict__ qn_t, const float* __restrict__ kn_t,
    __bf16* __restrict__ qbf, __bf16* __restrict__ kbf)
{
    const int l = blockIdx.x, t = threadIdx.x;
    const int wave = t >> 6, lane = t & 63;
    const bool is_img = (l < LI);
    const float* qw = is_img ? qn : qn_t;
    const float* kw = is_img ? kn : kn_t;
    const float kmask = is_img ? img_masks[l] : 1.0f;
    const float* qr = qraw + (size_t)l * DM;
    const float* kr = kraw + (size_t)l * DM;

    float2 qv[5], kv[5];
    float sq = 0.f, sk = 0.f;
#pragma unroll
    for (int j = 0; j < 5; j++) {
        int c2 = j * 256 + t;
        qv[j] = *(const float2*)(qr + 2 * c2);
        kv[j] = *(const float2*)(kr + 2 * c2);
        sq += qv[j].x * qv[j].x + qv[j].y * qv[j].y;
        sk += kv[j].x * kv[j].x + kv[j].y * kv[j].y;
    }
#pragma unroll
    for (int m = 32; m; m >>= 1) { sq += __shfl_xor(sq, m); sk += __shfl_xor(sk, m); }
    __shared__ float redq[4], redk[4];
    if (lane == 0) { redq[wave] = sq; redk[wave] = sk; }
    __syncthreads();
    sq = redq[0] + redq[1] + redq[2] + redq[3];
    sk = redk[0] + redk[1] + redk[2] + redk[3];
    const float rq = rsqrtf(sq * (1.0f / DM) + 1e-5f);
    const float rk = rsqrtf(sk * (1.0f / DM) + 1e-5f) * kmask;

#pragma unroll
    for (int j = 0; j < 5; j++) {
        int c2 = j * 256 + t;
        int c = 2 * c2;
        float4 rp = *(const float4*)(rope + ((size_t)l * 64 + (c2 & 63)) * 4);
        float2 w2q = *(const float2*)(qw + c);
        float2 w2k = *(const float2*)(kw + c);
        float x0 = qv[j].x * rq * w2q.x, x1 = qv[j].y * rq * w2q.y;
        bf16x2 oq = {(__bf16)(rp.x * x0 + rp.y * x1), (__bf16)(rp.z * x0 + rp.w * x1)};
        *(bf16x2*)(qbf + (size_t)l * DM + c) = oq;
        float y0 = kv[j].x * rk * w2k.x, y1 = kv[j].y * rk * w2k.y;
        bf16x2 ok = {(__bf16)(rp.x * y0 + rp.y * y1), (__bf16)(rp.z * y0 + rp.w * y1)};
        *(bf16x2*)(kbf + (size_t)l * DM + c) = ok;
    }
}

// ---------------- transpose V (L,DM) f32 -> (DM,L) bf16 ----------------

__global__ __launch_bounds__(256) void transpose_cvt_kernel(
    const float* __restrict__ src, __bf16* __restrict__ dst)
{
    __shared__ float tile[32][33];
    const int c0 = blockIdx.x * 32;
    const int r0 = blockIdx.y * 32;
    const int tc = threadIdx.x & 31, tr = threadIdx.x >> 5;
#pragma unroll
    for (int j = 0; j < 4; j++)
        tile[tr + j * 8][tc] = src[(size_t)(r0 + tr + j * 8) * DM + c0 + tc];
    __syncthreads();
#pragma unroll
    for (int j = 0; j < 4; j++)
        dst[(size_t)(c0 + tr + j * 8) * LSEQ + r0 + tc] = (__bf16)tile[tc][tr + j * 8];
}

// ---------------- flash attention ----------------

__global__ __launch_bounds__(256, 4) void flash_kernel(
    const __bf16* __restrict__ qb, const __bf16* __restrict__ kb,
    const __bf16* __restrict__ vt, __bf16* __restrict__ ob)
{
    __shared__ alignas(16) __bf16 sK[64 * DH];      // [kv 64][d 128]
    __shared__ alignas(16) __bf16 sV[DH * 64];      // [d 128][kv 64]
    __shared__ alignas(16) __bf16 sP[4 * 16 * 64];  // per-wave [q 16][kv 64]
    const int head = blockIdx.x;
    const int q0 = blockIdx.y * 64;
    const int t = threadIdx.x, wave = t >> 6, lane = t & 63;
    const int l15 = lane & 15, quad = lane >> 4;
    const int qrow = q0 + wave * 16 + l15;

    bf16x8 aq[4];
#pragma unroll
    for (int d = 0; d < 4; d++)
        aq[d] = *(const bf16x8*)(qb + (size_t)qrow * DM + head * DH + d * 32 + quad * 8);

    size_t koff[4], voff[4];
#pragma unroll
    for (int j = 0; j < 4; j++) {
        int ck = (wave * 4 + j) * 64 + lane;
        int krow = ck >> 4, ku = (ck & 15) ^ (krow & 7);
        koff[j] = (size_t)krow * DM + head * DH + ku * 8;
        int cv = (wave * 4 + j) * 64 + lane;
        int vrow = cv >> 3, vu = (cv & 7) ^ (vrow & 7);
        voff[j] = (size_t)(head * DH + vrow) * LSEQ + vu * 8;
    }

    f32x4 o[8];
#pragma unroll
    for (int i = 0; i < 8; i++) o[i] = f32x4{0.f, 0.f, 0.f, 0.f};
    float m_i = -INFINITY, l_i = 0.f;
    __bf16* pw = sP + wave * (16 * 64);

    for (int kv0 = 0; kv0 < LSEQ; kv0 += 64) {
        __syncthreads();
#pragma unroll
        for (int j = 0; j < 4; j++)
            async_copy16(kb + koff[j] + (size_t)kv0 * DM, (char*)sK + (wave * 4 + j) * 1024);
#pragma unroll
        for (int j = 0; j < 4; j++)
            async_copy16(vt + voff[j] + kv0, (char*)sV + (wave * 4 + j) * 1024);
        __syncthreads();

        f32x4 st[4];
#pragma unroll
        for (int b = 0; b < 4; b++) {
            st[b] = f32x4{0.f, 0.f, 0.f, 0.f};
#pragma unroll
            for (int d = 0; d < 4; d++) {
                int row = b * 16 + l15;
                bf16x8 ak = *(const bf16x8*)(sK + row * 128 + (((d * 4 + quad) ^ (row & 7)) * 8));
                st[b] = __builtin_amdgcn_mfma_f32_16x16x32_bf16(ak, aq[d], st[b], 0, 0, 0);
            }
        }

        float mx = m_i;
#pragma unroll
        for (int b = 0; b < 4; b++)
#pragma unroll
            for (int r = 0; r < 4; r++) { st[b][r] *= SCALE; mx = fmaxf(mx, st[b][r]); }
        mx = fmaxf(mx, __shfl_xor(mx, 16));
        mx = fmaxf(mx, __shfl_xor(mx, 32));
        const float al = __expf(m_i - mx);
        m_i = mx;
        float sum = 0.f;
#pragma unroll
        for (int b = 0; b < 4; b++)
#pragma unroll
            for (int r = 0; r < 4; r++) {
                float p = __expf(st[b][r] - mx);
                st[b][r] = p;
                sum += p;
            }
        sum += __shfl_xor(sum, 16);
        sum += __shfl_xor(sum, 32);
        l_i = l_i * al + sum;

#pragma unroll
        for (int b = 0; b < 4; b++) {
            bf16x4 pk = {(__bf16)st[b][0], (__bf16)st[b][1], (__bf16)st[b][2], (__bf16)st[b][3]};
            int u = 2 * b + (quad >> 1);
            *(bf16x4*)(pw + l15 * 64 + ((u ^ (l15 & 7)) * 8) + (quad & 1) * 4) = pk;
        }

        float alr[4];
#pragma unroll
        for (int r = 0; r < 4; r++) alr[r] = __shfl(al, quad * 4 + r);
#pragma unroll
        for (int i = 0; i < 8; i++) {
            f32x4 tmp = o[i];
            tmp[0] *= alr[0]; tmp[1] *= alr[1]; tmp[2] *= alr[2]; tmp[3] *= alr[3];
            o[i] = tmp;
        }
        __asm__ volatile("s_waitcnt lgkmcnt(0)" ::: "memory");

        bf16x8 ap0 = *(const bf16x8*)(pw + l15 * 64 + ((quad ^ (l15 & 7)) * 8));
        bf16x8 ap1 = *(const bf16x8*)(pw + l15 * 64 + (((4 + quad) ^ (l15 & 7)) * 8));
#pragma unroll
        for (int n2 = 0; n2 < 8; n2++) {
            int row = n2 * 16 + l15;
            bf16x8 bv0 = *(const bf16x8*)(sV + row * 64 + ((quad ^ (row & 7)) * 8));
            bf16x8 bv1 = *(const bf16x8*)(sV + row * 64 + (((4 + quad) ^ (row & 7)) * 8));
            o[n2] = __builtin_amdgcn_mfma_f32_16x16x32_bf16(ap0, bv0, o[n2], 0, 0, 0);
            o[n2] = __builtin_amdgcn_mfma_f32_16x16x32_bf16(ap1, bv1, o[n2], 0, 0, 0);
        }
    }

    const float inv = 1.0f / l_i;
    float invr[4];
#pragma unroll
    for (int r = 0; r < 4; r++) invr[r] = __shfl(inv, quad * 4 + r);
#pragma unroll
    for (int n2 = 0; n2 < 8; n2++)
#pragma unroll
        for (int r = 0; r < 4; r++)
            ob[(size_t)(q0 + wave * 16 + quad * 4 + r) * DM + head * DH + n2 * 16 + l15] =
                (__bf16)(o[n2][r] * invr[r]);
}

// ---------------- launch ----------------

extern "C" void kernel_launch(void* const* d_in, const int* in_sizes, int n_in,
                              void* d_out, int out_size, void* d_ws, size_t ws_size,
                              hipStream_t stream) {
    const float* img       = (const float*)d_in[0];
    const float* txt       = (const float*)d_in[1];
    const float* rope      = (const float*)d_in[2];
    const float* img_masks = (const float*)d_in[3];
    const float* Wq   = (const float*)d_in[4];  const float* bq   = (const float*)d_in[5];
    const float* Wk   = (const float*)d_in[6];  const float* bk   = (const float*)d_in[7];
    const float* Wv   = (const float*)d_in[8];  const float* bv   = (const float*)d_in[9];
    const float* Wo   = (const float*)d_in[10]; const float* bo   = (const float*)d_in[11];
    const float* Wq_t = (const float*)d_in[12]; const float* bq_t = (const float*)d_in[13];
    const float* Wk_t = (const float*)d_in[14]; const float* bk_t = (const float*)d_in[15];
    const float* Wv_t = (const float*)d_in[16]; const float* bv_t = (const float*)d_in[17];
    const float* Wo_t = (const float*)d_in[18]; const float* bo_t = (const float*)d_in[19];
    const float* qn   = (const float*)d_in[20]; const float* kn   = (const float*)d_in[21];
    const float* qn_t = (const float*)d_in[22]; const float* kn_t = (const float*)d_in[23];
    float* out = (float*)d_out;

    const size_t WELEM = (size_t)DM * DM;
    const size_t XELEM = (size_t)LSEQ * DM;

    __bf16* wbf  = (__bf16*)d_ws;
    __bf16* xbf  = wbf + 8 * WELEM;
    float*  qraw = (float*)(xbf + XELEM);
    float*  kraw = qraw + XELEM;
    float*  vraw = kraw + XELEM;
    __bf16* qbf  = (__bf16*)(vraw + XELEM);
    __bf16* kbf  = qbf + XELEM;
    __bf16* vt   = kbf + XELEM;
    __bf16* attnbf = (__bf16*)qraw;                // reuse (qraw dead after rmsrope)

    cvt8_kernel<<<dim3((int)(WELEM / 8 / 256), 8), 256, 0, stream>>>(
        Wq, Wk, Wv, Wo, Wq_t, Wk_t, Wv_t, Wo_t, wbf);
    cvt_kernel<<<dim3((LI * DM / 8 + 255) / 256), 256, 0, stream>>>(img, xbf, LI * DM / 8);
    cvt_kernel<<<dim3((LT * DM / 8 + 255) / 256), 256, 0, stream>>>(
        txt, xbf + (size_t)LI * DM, LT * DM / 8);

    gemm_qkv_kernel<<<dim3(60, 19), 256, 0, stream>>>(
        xbf, wbf, bq, bk, bv, bq_t, bk_t, bv_t, qraw, kraw, vraw);

    rmsrope_kernel<<<dim3(LSEQ), 256, 0, stream>>>(
        qraw, kraw, rope, img_masks, qn, kn, qn_t, kn_t, qbf, kbf);

    transpose_cvt_kernel<<<dim3(DM / 32, LSEQ / 32), 256, 0, stream>>>(vraw, vt);

    flash_kernel<<<dim3(NH, LSEQ / 64), 256, 0, stream>>>(qbf, kbf, vt, attnbf);

    gemm_out_kernel<<<dim3(20, 19), 256, 0, stream>>>(attnbf, wbf, bo, bo_t, out);
}